// Round 4
// baseline (419.653 us; speedup 1.0000x reference)
//
#include <hip/hip_runtime.h>

#define DIM 768
#define NHEADS 12
#define HDIM 64
#define BATCH 2
#define SEQ 2048
#define ROWS (BATCH*SEQ)   // 4096
#define KSPLIT 4

typedef __attribute__((ext_vector_type(8))) _Float16 f16x8;
typedef __attribute__((ext_vector_type(4))) _Float16 f16x4;
typedef __attribute__((ext_vector_type(4))) float    f32x4;

// ============================================================
// Fragment layout F(mt, kt): 16 rows x 32 cols of row-major M[R][C]:
//   frag[lane][j] = M[mt*16 + (lane&15)][kt*32 + (lane>>4)*8 + j]
// stored at dst[((mt*(C/32) + kt)*64 + lane)*8] (halves).
// Identical mapping for A- and B-operands of mfma_f32_16x16x32_f16.
// ============================================================

__global__ __launch_bounds__(256) void cvt_frag(
    const float* __restrict__ src, _Float16* __restrict__ dst, int R, int C)
{
    const int lane = threadIdx.x & 63;
    const int wid  = (blockIdx.x * 256 + threadIdx.x) >> 6;
    const int tc   = C >> 5;
    const int mt   = wid / tc, kt = wid % tc;
    if (mt * 16 >= R) return;
    const int c = lane & 15, quad = lane >> 4;
    const float* p = src + (size_t)(mt*16 + c) * C + kt*32 + quad*8;
    float4 v0 = *(const float4*)p;
    float4 v1 = *(const float4*)(p + 4);
    f16x8 o;
    o[0]=(_Float16)v0.x; o[1]=(_Float16)v0.y; o[2]=(_Float16)v0.z; o[3]=(_Float16)v0.w;
    o[4]=(_Float16)v1.x; o[5]=(_Float16)v1.y; o[6]=(_Float16)v1.z; o[7]=(_Float16)v1.w;
    *reinterpret_cast<f16x8*>(dst + ((size_t)wid * 64 + lane) * 8) = o;
}

// ---- all 3 projections in one kernel: 128x128 tiles, LDS double-buffer ----
// bid < 384: C = x * [Wq;Wk]^T  (M=4096, N=1536) -> Qf/Kf frags
// bid >= 384: C = Wv * x^T      (M=768, N=4096)  -> Vtf frags
__global__ __launch_bounds__(256) void gemm3(
    const _Float16* __restrict__ xf, const _Float16* __restrict__ wqkf,
    const _Float16* __restrict__ wvf,
    _Float16* __restrict__ Qf, _Float16* __restrict__ Kf, _Float16* __restrict__ Vtf)
{
    __shared__ _Float16 Abuf[2][8*512];   // 8 frags/kt = 8 KB per buf
    __shared__ _Float16 Bbuf[2][8*512];
    const int tid = threadIdx.x, lane = tid & 63, w = tid >> 6;
    const int c = lane & 15, quad = lane >> 4;

    const _Float16 *Af, *Bf;
    int mt0, nt0, mode;
    if ((int)blockIdx.x < 384) {
        int mt = blockIdx.x / 12, nt = blockIdx.x % 12;
        Af = xf; Bf = wqkf; mt0 = mt*8; nt0 = nt*8; mode = 0;
    } else {
        int v = blockIdx.x - 384;
        int mt = v / 32, nt = v % 32;
        Af = wvf; Bf = xf; mt0 = mt*8; nt0 = nt*8; mode = 1;
    }

    f32x4 acc[4][4] = {};
    f16x8 pre[4];
    // preload kt=0
#pragma unroll
    for (int u = 0; u < 4; ++u) {
        const int cc = w*4 + u;
        const _Float16* s = (cc < 8) ? Af + ((size_t)(mt0+cc)*24 + 0)*512
                                     : Bf + ((size_t)(nt0+cc-8)*24 + 0)*512;
        pre[u] = *(const f16x8*)(s + lane*8);
    }
#pragma unroll
    for (int u = 0; u < 4; ++u) {
        const int cc = w*4 + u;
        _Float16* d = (cc < 8) ? &Abuf[0][(cc&7)*512] : &Bbuf[0][(cc&7)*512];
        *(f16x8*)(d + lane*8) = pre[u];
    }
    __syncthreads();

    for (int kt = 0; kt < 24; ++kt) {
        const int cur = kt & 1;
        if (kt + 1 < 24) {
#pragma unroll
            for (int u = 0; u < 4; ++u) {
                const int cc = w*4 + u;
                const _Float16* s = (cc < 8) ? Af + ((size_t)(mt0+cc)*24 + kt+1)*512
                                             : Bf + ((size_t)(nt0+cc-8)*24 + kt+1)*512;
                pre[u] = *(const f16x8*)(s + lane*8);
            }
        }
        f16x8 a[4], b[4];
#pragma unroll
        for (int i = 0; i < 4; ++i)
            a[i] = *(const f16x8*)(&Abuf[cur][((w>>1)*4 + i)*512] + lane*8);
#pragma unroll
        for (int j = 0; j < 4; ++j)
            b[j] = *(const f16x8*)(&Bbuf[cur][((w&1)*4 + j)*512] + lane*8);
#pragma unroll
        for (int i = 0; i < 4; ++i)
#pragma unroll
            for (int j = 0; j < 4; ++j)
                acc[i][j] = __builtin_amdgcn_mfma_f32_16x16x32_f16(a[i], b[j], acc[i][j], 0,0,0);
        if (kt + 1 < 24) {
#pragma unroll
            for (int u = 0; u < 4; ++u) {
                const int cc = w*4 + u;
                _Float16* d = (cc < 8) ? &Abuf[(kt+1)&1][(cc&7)*512] : &Bbuf[(kt+1)&1][(cc&7)*512];
                *(f16x8*)(d + lane*8) = pre[u];
            }
        }
        __syncthreads();
    }

    // epilogue: per-wave 32x32 transposes -> frag-layout stores
    _Float16* L = &Abuf[0][0] + w*1280;   // 32x40 halves per wave
#pragma unroll
    for (int i2 = 0; i2 < 2; ++i2)
#pragma unroll
        for (int j2 = 0; j2 < 2; ++j2) {
#pragma unroll
            for (int ii = 0; ii < 2; ++ii)
#pragma unroll
                for (int jj = 0; jj < 2; ++jj)
#pragma unroll
                    for (int r = 0; r < 4; ++r)
                        L[(ii*16 + quad*4 + r)*40 + jj*16 + c] =
                            (_Float16)acc[i2*2+ii][j2*2+jj][r];
#pragma unroll
            for (int ii = 0; ii < 2; ++ii) {
                f16x8 v = *(const f16x8*)(L + (ii*16 + c)*40 + quad*8);
                const int mtg  = mt0 + (w>>1)*4 + i2*2 + ii;
                const int nt32 = (nt0 + (w&1)*4)/2 + j2;
                _Float16* dst;
                if (mode == 0)
                    dst = (nt32 < 24) ? Qf + ((size_t)(mtg*24 + nt32)*64 + lane)*8
                                      : Kf + ((size_t)(mtg*24 + nt32 - 24)*64 + lane)*8;
                else
                    dst = Vtf + ((size_t)(mtg*128 + nt32)*64 + lane)*8;
                *(f16x8*)dst = v;
            }
        }
}

// ---- fused attention, heads-softmax, LDS-staged K/V ----
// grid: 2 b x 4 ks x 32 qb = 256 blocks, 512 thr (8 waves).
// Block = 64 q rows x 512 keys; 32 iters of 16 keys (pairs of 2 for PV).
// wave (qi = w>>1, g = w&1): phase1 scores 6 heads (g half) for q-tile qi;
// cross-wave head exchange via S_lds; phase2 PV for 12 heads x dt-half g
// over 32-key P tiles (K=32 MFMA). K/V staged to LDS with 1-2 iter lead.
__global__ __launch_bounds__(512, 2) void attn_kernel(
    const _Float16* __restrict__ Qf, const _Float16* __restrict__ Kf,
    const _Float16* __restrict__ Vtf,
    float* __restrict__ out,          // ks==0 partial
    _Float16* __restrict__ part)      // [3][4096][768] f16, ks=1..3
{
    __shared__ _Float16 K_lds[24*512];    // 24 KB: 16-key tile (24 frags)
    __shared__ _Float16 V_lds[48*512];    // 48 KB: 32-key tile (48 frags)
    __shared__ _Float16 S_lds[4*12*64*4]; // 24 KB: score exchange, f16x4/lane
    __shared__ _Float16 P_lds[4*12*16*40];// 60 KB: P, 32 keys + pad8
    const int tid = threadIdx.x, lane = tid & 63, w = tid >> 6;
    const int c = lane & 15, quad = lane >> 4;
    const int qi = w >> 1, g = w & 1;

    const int bid = blockIdx.x;
    const int qb = bid & 31;
    const int ks = (bid >> 5) & 3;
    const int b  = bid >> 7;
    const int qrow0 = b*SEQ + qb*64;
    const int qt16  = (qrow0 >> 4) + qi;
    const int kb16  = (b*SEQ + ks*512) >> 4;
    const int kb32  = kb16 >> 1;

    // hoist Q frags for this wave's q-tile + its 6 heads
    f16x8 qreg[12];
#pragma unroll
    for (int j = 0; j < 12; ++j)
        qreg[j] = *(const f16x8*)(Qf + ((size_t)(qt16*24 + g*12 + j)*64 + lane)*8);

    // ---- preamble: stage K[0], V[pair 0]; prefetch K[1], V[pair 1] ----
    f16x8 kpre[3], vpre[6];
    {
        const _Float16* kg0 = Kf + (size_t)(kb16 + 0)*24*512;
        f16x8 k0[3], v0[6];
#pragma unroll
        for (int u = 0; u < 3; ++u)
            k0[u] = *(const f16x8*)(kg0 + (w*3+u)*512 + lane*8);
#pragma unroll
        for (int u = 0; u < 6; ++u)
            v0[u] = *(const f16x8*)(Vtf + ((size_t)(w*6+u)*128 + kb32)*512 + lane*8);
#pragma unroll
        for (int u = 0; u < 3; ++u)
            *(f16x8*)(K_lds + (w*3+u)*512 + lane*8) = k0[u];
#pragma unroll
        for (int u = 0; u < 6; ++u)
            *(f16x8*)(V_lds + (w*6+u)*512 + lane*8) = v0[u];
        const _Float16* kg1 = Kf + (size_t)(kb16 + 1)*24*512;
#pragma unroll
        for (int u = 0; u < 3; ++u)
            kpre[u] = *(const f16x8*)(kg1 + (w*3+u)*512 + lane*8);
#pragma unroll
        for (int u = 0; u < 6; ++u)
            vpre[u] = *(const f16x8*)(Vtf + ((size_t)(w*6+u)*128 + kb32 + 1)*512 + lane*8);
    }
    __syncthreads();

    f32x4 o_acc[12][2] = {};

    for (int p = 0; p < 16; ++p) {
#pragma unroll
        for (int sub = 0; sub < 2; ++sub) {
            const int i = p*2 + sub;
            // ---- phase 1: scores for own 6 heads, 16 keys ----
            f32x4 s[6];
#pragma unroll
            for (int hh = 0; hh < 6; ++hh) {
                f16x8 ka = *(const f16x8*)(K_lds + (g*12 + hh*2    )*512 + lane*8);
                f16x8 kb = *(const f16x8*)(K_lds + (g*12 + hh*2 + 1)*512 + lane*8);
                f32x4 acc = {};
                acc = __builtin_amdgcn_mfma_f32_16x16x32_f16(qreg[hh*2],   ka, acc, 0,0,0);
                acc = __builtin_amdgcn_mfma_f32_16x16x32_f16(qreg[hh*2+1], kb, acc, 0,0,0);
                s[hh] = acc;   // S[q=quad*4+r][k=c]
            }
            // exchange: write own 6 head-scores (f16) for partner wave
#pragma unroll
            for (int hh = 0; hh < 6; ++hh) {
                f16x4 sv;
                sv[0]=(_Float16)s[hh][0]; sv[1]=(_Float16)s[hh][1];
                sv[2]=(_Float16)s[hh][2]; sv[3]=(_Float16)s[hh][3];
                *(f16x4*)(S_lds + ((size_t)(qi*12 + g*6 + hh)*64 + lane)*4) = sv;
            }
            __syncthreads();   // A
            // ---- softmax over all 12 heads (read exchanged, rounded) ----
            f16x4 sa[12];
#pragma unroll
            for (int h = 0; h < 12; ++h)
                sa[h] = *(const f16x4*)(S_lds + ((size_t)(qi*12 + h)*64 + lane)*4);
#pragma unroll
            for (int r = 0; r < 4; ++r) {
                float v[12];
#pragma unroll
                for (int h = 0; h < 12; ++h) v[h] = (float)sa[h][r];
                float m = v[0];
#pragma unroll
                for (int h = 1; h < 12; ++h) m = fmaxf(m, v[h]);
                float sum = 0.f, e[12];
#pragma unroll
                for (int h = 0; h < 12; ++h) { e[h] = __expf(v[h] - m); sum += e[h]; }
                const float inv = 1.0f / (sum * 27.712812921102035f);  // /sqrt(768)
#pragma unroll
                for (int hh = 0; hh < 6; ++hh)
                    P_lds[((qi*12 + g*6 + hh)*16 + quad*4 + r)*40 + sub*16 + c] =
                        (_Float16)(e[g*6 + hh] * inv);
            }
            // ---- staging: K[i+1] write / K[i+2] load; V[p] write / V[p+1] load ----
            if (i + 1 < 32) {
#pragma unroll
                for (int u = 0; u < 3; ++u)
                    *(f16x8*)(K_lds + (w*3+u)*512 + lane*8) = kpre[u];
                if (i + 2 < 32) {
                    const _Float16* kg = Kf + (size_t)(kb16 + i + 2)*24*512;
#pragma unroll
                    for (int u = 0; u < 3; ++u)
                        kpre[u] = *(const f16x8*)(kg + (w*3+u)*512 + lane*8);
                }
            }
            if (p >= 1) {
#pragma unroll
                for (int u = 0; u < 3; ++u) {
                    const int j = w*6 + sub*3 + u;
                    *(f16x8*)(V_lds + j*512 + lane*8) = vpre[sub*3 + u];
                }
                if (p + 1 < 16) {
#pragma unroll
                    for (int u = 0; u < 3; ++u) {
                        const int j = w*6 + sub*3 + u;
                        vpre[sub*3 + u] = *(const f16x8*)(
                            Vtf + ((size_t)j*128 + kb32 + p + 1)*512 + lane*8);
                    }
                }
            }
            __syncthreads();   // B
            // ---- phase 2 (every 2nd iter): PV over 32 keys, K=32 MFMA ----
            if (sub == 1) {
#pragma unroll
                for (int h = 0; h < 12; ++h) {
                    f16x8 pf = *(const f16x8*)(P_lds + ((qi*12 + h)*16 + c)*40 + quad*8);
#pragma unroll
                    for (int dd = 0; dd < 2; ++dd) {
                        f16x8 vf = *(const f16x8*)(V_lds + (h*4 + g*2 + dd)*512 + lane*8);
                        o_acc[h][dd] = __builtin_amdgcn_mfma_f32_16x16x32_f16(pf, vf, o_acc[h][dd], 0,0,0);
                    }
                }
            }
        }
    }
    // ---- epilogue ----
    if (ks == 0) {
#pragma unroll
        for (int h = 0; h < 12; ++h)
#pragma unroll
            for (int dd = 0; dd < 2; ++dd) {
                const int col = h*64 + (g*2 + dd)*16 + c;
#pragma unroll
                for (int r = 0; r < 4; ++r) {
                    const int row = qrow0 + qi*16 + quad*4 + r;
                    out[(size_t)row * DIM + col] = o_acc[h][dd][r];
                }
            }
    } else {
        _Float16* dst = part + (size_t)(ks - 1) * ROWS * DIM;
#pragma unroll
        for (int h = 0; h < 12; ++h)
#pragma unroll
            for (int dd = 0; dd < 2; ++dd) {
                const int col = h*64 + (g*2 + dd)*16 + c;
#pragma unroll
                for (int r = 0; r < 4; ++r) {
                    const int row = qrow0 + qi*16 + quad*4 + r;
                    dst[(size_t)row * DIM + col] = (_Float16)o_acc[h][dd][r];
                }
            }
    }
}

// ---- out += sum of 3 f16 partials ----
__global__ __launch_bounds__(256) void reduce_add4(
    float* __restrict__ out, const _Float16* __restrict__ part, int n4)
{
    int i = blockIdx.x * 256 + threadIdx.x;
    if (i >= n4) return;
    float4 o = reinterpret_cast<float4*>(out)[i];
    const size_t N = (size_t)ROWS * DIM;
#pragma unroll
    for (int p = 0; p < 3; ++p) {
        f16x4 v = reinterpret_cast<const f16x4*>(part + p * N)[i];
        o.x += (float)v[0]; o.y += (float)v[1]; o.z += (float)v[2]; o.w += (float)v[3];
    }
    reinterpret_cast<float4*>(out)[i] = o;
}

// ------------------------------- launch ----------------------------------
extern "C" void kernel_launch(void* const* d_in, const int* in_sizes, int n_in,
                              void* d_out, int out_size, void* d_ws, size_t ws_size,
                              hipStream_t stream)
{
    const float* x  = (const float*)d_in[0];
    const float* Wq = (const float*)d_in[1];
    const float* Wk = (const float*)d_in[2];
    const float* Wv = (const float*)d_in[3];

    _Float16* ws  = (_Float16*)d_ws;
    const size_t XS = (size_t)ROWS * DIM;   // 3145728
    const size_t WS = (size_t)DIM * DIM;    // 589824
    _Float16* xf   = ws;
    _Float16* wqf  = xf  + XS;              // wq+wk adjacent = stacked [Wq;Wk]
    _Float16* wkf  = wqf + WS;
    _Float16* wvf  = wkf + WS;
    _Float16* Qf   = wvf + WS;
    _Float16* Kf   = Qf  + XS;
    _Float16* Vtf  = Kf  + XS;
    _Float16* part = Vtf + XS;              // 3 * XS f16 partials

    cvt_frag<<<(ROWS/16)*(DIM/32)/4, 256, 0, stream>>>(x,  xf,  ROWS, DIM);
    cvt_frag<<<(DIM/16)*(DIM/32)/4,  256, 0, stream>>>(Wq, wqf, DIM, DIM);
    cvt_frag<<<(DIM/16)*(DIM/32)/4,  256, 0, stream>>>(Wk, wkf, DIM, DIM);
    cvt_frag<<<(DIM/16)*(DIM/32)/4,  256, 0, stream>>>(Wv, wvf, DIM, DIM);

    gemm3<<<576, 256, 0, stream>>>(xf, wqf, wvf, Qf, Kf, Vtf);

    attn_kernel<<<BATCH * KSPLIT * 32, 512, 0, stream>>>(
        Qf, Kf, Vtf, (float*)d_out, part);
    reduce_add4<<<(int)(XS/4 + 255)/256, 256, 0, stream>>>(
        (float*)d_out, part, (int)(XS/4));
}

// Round 5
// 276.659 us; speedup vs baseline: 1.5169x; 1.5169x over previous
//
#include <hip/hip_runtime.h>

#define DIM 768
#define NHEADS 12
#define HDIM 64
#define BATCH 2
#define SEQ 2048
#define ROWS (BATCH*SEQ)   // 4096
#define KSPLIT 2

typedef __attribute__((ext_vector_type(8))) _Float16 f16x8;
typedef __attribute__((ext_vector_type(4))) _Float16 f16x4;
typedef __attribute__((ext_vector_type(4))) float    f32x4;

// async global->LDS DMA, 16 B per lane; LDS dest = uniform base + lane*16
__device__ __forceinline__ void dma16(const _Float16* g, _Float16* l) {
    __builtin_amdgcn_global_load_lds(
        (const __attribute__((address_space(1))) unsigned int*)g,
        (__attribute__((address_space(3))) unsigned int*)l, 16, 0, 0);
}

// ============================================================
// Fragment layout F(mt, kt): 16 rows x 32 cols of row-major M[R][C]:
//   frag[lane][j] = M[mt*16 + (lane&15)][kt*32 + (lane>>4)*8 + j]
// stored at dst[((mt*(C/32) + kt)*64 + lane)*8] (halves).
// Same mapping for A- and B-operands of mfma_f32_16x16x32_f16.
// ============================================================

// ---- all 4 fp32->f16 frag conversions in one launch (all have C=768) ----
__global__ __launch_bounds__(256) void cvt_all(
    const float* __restrict__ x,  const float* __restrict__ wq,
    const float* __restrict__ wk, const float* __restrict__ wv,
    _Float16* __restrict__ xf,  _Float16* __restrict__ wqf,
    _Float16* __restrict__ wkf, _Float16* __restrict__ wvf)
{
    const int lane = threadIdx.x & 63;
    const int wid  = (blockIdx.x * 256 + threadIdx.x) >> 6;
    const float* src; _Float16* dst; int t;
    if (wid < 6144)      { src = x;  dst = xf;  t = wid;        }
    else if (wid < 7296) { src = wq; dst = wqf; t = wid - 6144; }
    else if (wid < 8448) { src = wk; dst = wkf; t = wid - 7296; }
    else                 { src = wv; dst = wvf; t = wid - 8448; }
    const int c = lane & 15, quad = lane >> 4;
    const int mt = t / 24, kt = t % 24;
    const float* p = src + (size_t)(mt*16 + c) * 768 + kt*32 + quad*8;
    float4 v0 = *(const float4*)p;
    float4 v1 = *(const float4*)(p + 4);
    f16x8 o;
    o[0]=(_Float16)v0.x; o[1]=(_Float16)v0.y; o[2]=(_Float16)v0.z; o[3]=(_Float16)v0.w;
    o[4]=(_Float16)v1.x; o[5]=(_Float16)v1.y; o[6]=(_Float16)v1.z; o[7]=(_Float16)v1.w;
    *reinterpret_cast<f16x8*>(dst + ((size_t)t * 64 + lane) * 8) = o;
}

// ---- all 3 projections: 128x128 tiles, LDS double-buffer (round-4 gemm3) ----
__global__ __launch_bounds__(256) void gemm3(
    const _Float16* __restrict__ xf, const _Float16* __restrict__ wqkf,
    const _Float16* __restrict__ wvf,
    _Float16* __restrict__ Qf, _Float16* __restrict__ Kf, _Float16* __restrict__ Vtf)
{
    __shared__ _Float16 Abuf[2][8*512];
    __shared__ _Float16 Bbuf[2][8*512];
    const int tid = threadIdx.x, lane = tid & 63, w = tid >> 6;
    const int c = lane & 15, quad = lane >> 4;

    const _Float16 *Af, *Bf;
    int mt0, nt0, mode;
    if ((int)blockIdx.x < 384) {
        int mt = blockIdx.x / 12, nt = blockIdx.x % 12;
        Af = xf; Bf = wqkf; mt0 = mt*8; nt0 = nt*8; mode = 0;
    } else {
        int v = blockIdx.x - 384;
        int mt = v / 32, nt = v % 32;
        Af = wvf; Bf = xf; mt0 = mt*8; nt0 = nt*8; mode = 1;
    }

    f32x4 acc[4][4] = {};
    f16x8 pre[4];
#pragma unroll
    for (int u = 0; u < 4; ++u) {
        const int cc = w*4 + u;
        const _Float16* s = (cc < 8) ? Af + ((size_t)(mt0+cc)*24 + 0)*512
                                     : Bf + ((size_t)(nt0+cc-8)*24 + 0)*512;
        pre[u] = *(const f16x8*)(s + lane*8);
    }
#pragma unroll
    for (int u = 0; u < 4; ++u) {
        const int cc = w*4 + u;
        _Float16* d = (cc < 8) ? &Abuf[0][(cc&7)*512] : &Bbuf[0][(cc&7)*512];
        *(f16x8*)(d + lane*8) = pre[u];
    }
    __syncthreads();

    for (int kt = 0; kt < 24; ++kt) {
        const int cur = kt & 1;
        if (kt + 1 < 24) {
#pragma unroll
            for (int u = 0; u < 4; ++u) {
                const int cc = w*4 + u;
                const _Float16* s = (cc < 8) ? Af + ((size_t)(mt0+cc)*24 + kt+1)*512
                                             : Bf + ((size_t)(nt0+cc-8)*24 + kt+1)*512;
                pre[u] = *(const f16x8*)(s + lane*8);
            }
        }
        f16x8 a[4], b[4];
#pragma unroll
        for (int i = 0; i < 4; ++i)
            a[i] = *(const f16x8*)(&Abuf[cur][((w>>1)*4 + i)*512] + lane*8);
#pragma unroll
        for (int j = 0; j < 4; ++j)
            b[j] = *(const f16x8*)(&Bbuf[cur][((w&1)*4 + j)*512] + lane*8);
#pragma unroll
        for (int i = 0; i < 4; ++i)
#pragma unroll
            for (int j = 0; j < 4; ++j)
                acc[i][j] = __builtin_amdgcn_mfma_f32_16x16x32_f16(a[i], b[j], acc[i][j], 0,0,0);
        if (kt + 1 < 24) {
#pragma unroll
            for (int u = 0; u < 4; ++u) {
                const int cc = w*4 + u;
                _Float16* d = (cc < 8) ? &Abuf[(kt+1)&1][(cc&7)*512] : &Bbuf[(kt+1)&1][(cc&7)*512];
                *(f16x8*)(d + lane*8) = pre[u];
            }
        }
        __syncthreads();
    }

    _Float16* L = &Abuf[0][0] + w*1280;
#pragma unroll
    for (int i2 = 0; i2 < 2; ++i2)
#pragma unroll
        for (int j2 = 0; j2 < 2; ++j2) {
#pragma unroll
            for (int ii = 0; ii < 2; ++ii)
#pragma unroll
                for (int jj = 0; jj < 2; ++jj)
#pragma unroll
                    for (int r = 0; r < 4; ++r)
                        L[(ii*16 + quad*4 + r)*40 + jj*16 + c] =
                            (_Float16)acc[i2*2+ii][j2*2+jj][r];
#pragma unroll
            for (int ii = 0; ii < 2; ++ii) {
                f16x8 v = *(const f16x8*)(L + (ii*16 + c)*40 + quad*8);
                const int mtg  = mt0 + (w>>1)*4 + i2*2 + ii;
                const int nt32 = (nt0 + (w&1)*4)/2 + j2;
                _Float16* dst;
                if (mode == 0)
                    dst = (nt32 < 24) ? Qf + ((size_t)(mtg*24 + nt32)*64 + lane)*8
                                      : Kf + ((size_t)(mtg*24 + nt32 - 24)*64 + lane)*8;
                else
                    dst = Vtf + ((size_t)(mtg*128 + nt32)*64 + lane)*8;
                *(f16x8*)dst = v;
            }
        }
}

// ---- fused attention: K via async DMA double-buffer, pinned 2 waves/EU ----
// grid: 2b x KSPLIT x 64qb = 256 blocks, 512 thr (8 waves), 1 block/CU.
// wave w = (qi = w>>2, g = (w>>1)&1, kj = w&1), dt = w&3.
// Per 32-key iter: DMA next K tile (48 frags, 6/wave, zero VGPR);
// phase1: 6 heads (g) x 16 keys (kj) for q-tile qi; f16 score exchange
// with partner (w^2) for the 12-head softmax; phase2: 12 heads x dt.
__global__ __launch_bounds__(512) __attribute__((amdgpu_waves_per_eu(2, 2)))
void attn_kernel(
    const _Float16* __restrict__ Qf, const _Float16* __restrict__ Kf,
    const _Float16* __restrict__ Vtf,
    float* __restrict__ out,          // ks==0 partial (covers all elements)
    _Float16* __restrict__ part)      // [4096][768] f16, ks==1
{
    __shared__ _Float16 Kbuf[2][48*512];     // 96 KB (32-key K tiles)
    __shared__ _Float16 P_lds[2*12*16*40];   // 30 KB
    __shared__ _Float16 S_lds[2*2*12*64*4];  // 24 KB score exchange
    const int tid = threadIdx.x, lane = tid & 63, w = tid >> 6;
    const int c = lane & 15, quad = lane >> 4;
    const int qi = w >> 2, g = (w >> 1) & 1, kj = w & 1, dt = w & 3;

    const int bid = blockIdx.x;
    const int qb = bid & 63;
    const int ks = (bid >> 6) & (KSPLIT - 1);
    const int b  = bid >> 7;
    const int qrow0 = b*SEQ + qb*32;
    const int qt16  = (qrow0 >> 4) + qi;
    const int kb16  = (b*SEQ + ks*(SEQ/KSPLIT)) >> 4;
    const int kb32  = kb16 >> 1;

    // Q frags: q-tile qi, heads g*6..g*6+5 (48 VGPRs)
    f16x8 qreg[12];
#pragma unroll
    for (int u = 0; u < 12; ++u)
        qreg[u] = *(const f16x8*)(Qf + ((size_t)(qt16*24 + g*12 + u)*64 + lane)*8);

    // preamble: DMA K tile 0 into buf 0 (frag f = w*6+u; e=f/24, j=f%24)
#pragma unroll
    for (int u = 0; u < 6; ++u) {
        const int f = w*6 + u, e = w >> 2, j = (w&3)*6 + u;
        dma16(Kf + ((size_t)(kb16 + e)*24 + j)*512 + lane*8,
              &Kbuf[0][f*512]);
    }
    __syncthreads();

    f32x4 o_acc[12] = {};

    const int NIT = (SEQ / KSPLIT) / 32;     // 32 iters
    for (int i = 0; i < NIT; ++i) {
        const int cur = i & 1;
        // ---- DMA next K tile ----
        if (i + 1 < NIT) {
            const int nxt = (i + 1) & 1;
#pragma unroll
            for (int u = 0; u < 6; ++u) {
                const int f = w*6 + u, e = w >> 2, j = (w&3)*6 + u;
                dma16(Kf + ((size_t)(kb16 + 2*(i+1) + e)*24 + j)*512 + lane*8,
                      &Kbuf[nxt][f*512]);
            }
        }
        // ---- phase 1: 6 heads x 16 keys (kj half) ----
        f32x4 s6[6];
#pragma unroll
        for (int hh = 0; hh < 6; ++hh) {
            f16x8 ka = *(const f16x8*)(&Kbuf[cur][(kj*24 + g*12 + hh*2    )*512] + lane*8);
            f16x8 kb = *(const f16x8*)(&Kbuf[cur][(kj*24 + g*12 + hh*2 + 1)*512] + lane*8);
            f32x4 acc = {};
            acc = __builtin_amdgcn_mfma_f32_16x16x32_f16(qreg[hh*2],   ka, acc, 0,0,0);
            acc = __builtin_amdgcn_mfma_f32_16x16x32_f16(qreg[hh*2+1], kb, acc, 0,0,0);
            s6[hh] = acc;   // S[q=quad*4+r][k=c]
        }
        // ---- score exchange (f16) for heads-softmax ----
#pragma unroll
        for (int hh = 0; hh < 6; ++hh) {
            f16x4 sv;
            sv[0]=(_Float16)s6[hh][0]; sv[1]=(_Float16)s6[hh][1];
            sv[2]=(_Float16)s6[hh][2]; sv[3]=(_Float16)s6[hh][3];
            *(f16x4*)(S_lds + (((qi*2 + kj)*12 + g*6 + hh)*64 + lane)*4) = sv;
        }
        __syncthreads();   // A
        f16x4 sa[12];
#pragma unroll
        for (int h = 0; h < 12; ++h)
            sa[h] = *(const f16x4*)(S_lds + (((qi*2 + kj)*12 + h)*64 + lane)*4);
#pragma unroll
        for (int r = 0; r < 4; ++r) {
            float v[12];
#pragma unroll
            for (int h = 0; h < 12; ++h) v[h] = (float)sa[h][r];
            float m = v[0];
#pragma unroll
            for (int h = 1; h < 12; ++h) m = fmaxf(m, v[h]);
            float sum = 0.f, e[12];
#pragma unroll
            for (int h = 0; h < 12; ++h) { e[h] = __expf(v[h] - m); sum += e[h]; }
            const float inv = 1.0f / (sum * 27.712812921102035f);  // /sqrt(768)
#pragma unroll
            for (int hh = 0; hh < 6; ++hh)
                P_lds[((qi*12 + g*6 + hh)*16 + quad*4 + r)*40 + kj*16 + c] =
                    (_Float16)(e[g*6 + hh] * inv);
        }
        // ---- V frags for this iter (regs, 12 in flight) ----
        f16x8 vf[12];
#pragma unroll
        for (int h = 0; h < 12; ++h)
            vf[h] = *(const f16x8*)(Vtf + ((size_t)((h*4 + dt)*128 + kb32 + i)*512 + lane*8));
        __syncthreads();   // B (P visible)
        // ---- phase 2: PV, 12 heads x 1 d-tile, K=32 over the 32 keys ----
#pragma unroll
        for (int h = 0; h < 12; ++h) {
            f16x8 pf = *(const f16x8*)(P_lds + ((qi*12 + h)*16 + c)*40 + quad*8);
            o_acc[h] = __builtin_amdgcn_mfma_f32_16x16x32_f16(pf, vf[h], o_acc[h], 0,0,0);
        }
    }
    // ---- epilogue ----
    if (ks == 0) {
#pragma unroll
        for (int h = 0; h < 12; ++h) {
            const int col = h*64 + dt*16 + c;
#pragma unroll
            for (int r = 0; r < 4; ++r)
                out[(size_t)(qrow0 + qi*16 + quad*4 + r) * DIM + col] = o_acc[h][r];
        }
    } else {
#pragma unroll
        for (int h = 0; h < 12; ++h) {
            const int col = h*64 + dt*16 + c;
#pragma unroll
            for (int r = 0; r < 4; ++r)
                part[(size_t)(qrow0 + qi*16 + quad*4 + r) * DIM + col] =
                    (_Float16)o_acc[h][r];
        }
    }
}

// ---- out += f16 partial ----
__global__ __launch_bounds__(256) void reduce_add(
    float* __restrict__ out, const _Float16* __restrict__ part, int n4)
{
    int i = blockIdx.x * 256 + threadIdx.x;
    if (i >= n4) return;
    float4 o = reinterpret_cast<float4*>(out)[i];
    f16x4 v = reinterpret_cast<const f16x4*>(part)[i];
    o.x += (float)v[0]; o.y += (float)v[1]; o.z += (float)v[2]; o.w += (float)v[3];
    reinterpret_cast<float4*>(out)[i] = o;
}

// ------------------------------- launch ----------------------------------
extern "C" void kernel_launch(void* const* d_in, const int* in_sizes, int n_in,
                              void* d_out, int out_size, void* d_ws, size_t ws_size,
                              hipStream_t stream)
{
    const float* x  = (const float*)d_in[0];
    const float* Wq = (const float*)d_in[1];
    const float* Wk = (const float*)d_in[2];
    const float* Wv = (const float*)d_in[3];

    _Float16* ws  = (_Float16*)d_ws;
    const size_t XS = (size_t)ROWS * DIM;   // 3145728
    const size_t WS = (size_t)DIM * DIM;    // 589824
    _Float16* xf   = ws;
    _Float16* wqf  = xf  + XS;              // wq+wk adjacent = stacked [Wq;Wk]
    _Float16* wkf  = wqf + WS;
    _Float16* wvf  = wkf + WS;
    _Float16* Qf   = wvf + WS;
    _Float16* Kf   = Qf  + XS;
    _Float16* Vtf  = Kf  + XS;
    _Float16* part = Vtf + XS;              // XS f16 partial (ks==1)

    cvt_all<<<2400, 256, 0, stream>>>(x, Wq, Wk, Wv, xf, wqf, wkf, wvf);
    gemm3<<<576, 256, 0, stream>>>(xf, wqf, wvf, Qf, Kf, Vtf);
    attn_kernel<<<BATCH * KSPLIT * 64, 512, 0, stream>>>(
        Qf, Kf, Vtf, (float*)d_out, part);
    reduce_add<<<(int)(XS/4 + 255)/256, 256, 0, stream>>>(
        (float*)d_out, part, (int)(XS/4));
}